// Round 15
// baseline (209.215 us; speedup 1.0000x reference)
//
#include <hip/hip_runtime.h>
#include <hip/hip_bf16.h>

typedef __attribute__((ext_vector_type(8))) short short8;
typedef __attribute__((ext_vector_type(4))) short short4v;
typedef __attribute__((ext_vector_type(4))) float f32x4;

#define MFMA16(a, b, c) __builtin_amdgcn_mfma_f32_16x16x32_bf16(a, b, c, 0, 0, 0)
#define QK_SCALE_LOG2E 0.18033688011112042f  // (1/8) * log2(e)

__device__ __forceinline__ short f2bf(float x) {
  union { float f; unsigned u; } v; v.f = x;
  unsigned u = v.u;
  u += 0x7FFFu + ((u >> 16) & 1u);  // RNE
  return (short)(u >> 16);
}
__device__ __forceinline__ short f2bf_trunc(float x) {
  union { float f; unsigned u; } v; v.f = x;
  return (short)(v.u >> 16);
}

__device__ __forceinline__ void gload16(const void* g, void* l) {
  __builtin_amdgcn_global_load_lds(
      (const __attribute__((address_space(1))) unsigned int*)g,
      (__attribute__((address_space(3))) unsigned int*)l, 16, 0, 0);
}

// ---------------------------------------------------------------------------
// Pre-pass kernels
// ---------------------------------------------------------------------------
__global__ __launch_bounds__(256) void conv_bf16_kernel(
    const float* __restrict__ in, short* __restrict__ out, int n4) {
  int i = blockIdx.x * 256 + threadIdx.x;
  if (i >= n4) return;
  f32x4 v = *(const f32x4*)(in + (size_t)i * 4);
  short4v s;
  s[0] = f2bf(v[0]); s[1] = f2bf(v[1]); s[2] = f2bf(v[2]); s[3] = f2bf(v[3]);
  *(short4v*)(out + (size_t)i * 4) = s;
}

// enc (4 x 576 x 768 f32) -> text_bf (4*512 x 768) + ip_bf (4*64 x 768)
__global__ __launch_bounds__(256) void enc_pack_kernel(
    const float* __restrict__ enc, short* __restrict__ text,
    short* __restrict__ ip) {
  int i4 = blockIdx.x * 256 + threadIdx.x;
  int i = i4 * 4;
  if (i >= 4 * 576 * 768) return;
  int c = i % 768;
  int rs = i / 768;
  int b = rs / 576, s = rs % 576;
  f32x4 v = *(const f32x4*)(enc + i);
  short4v o;
  o[0] = f2bf(v[0]); o[1] = f2bf(v[1]); o[2] = f2bf(v[2]); o[3] = f2bf(v[3]);
  if (s < 512)
    *(short4v*)(text + (size_t)(b * 512 + s) * 768 + c) = o;
  else
    *(short4v*)(ip + (size_t)(b * 64 + (s - 512)) * 768 + c) = o;
}

// All weight transposes fused -> (N x K) bf16 row-major.
__global__ __launch_bounds__(256) void prep_weights_kernel(
    const float* __restrict__ wq, const float* __restrict__ wo,
    const float* __restrict__ wk, const float* __restrict__ wv,
    const float* __restrict__ wkip, const float* __restrict__ wvip,
    short* __restrict__ wqT, short* __restrict__ woT,
    short* __restrict__ wkvT, short* __restrict__ wkvipT) {
  __shared__ float tile[32][33];
  const int z = blockIdx.z;
  const float* src; short* dst; int N, row_off;
  if (z == 0)      { src = wq;   dst = wqT;    N = 1536; row_off = 0; }
  else if (z == 1) { src = wo;   dst = woT;    N = 1536; row_off = 0; }
  else if (z == 2) { src = wk;   dst = wkvT;   N = 768;  row_off = 0; }
  else if (z == 3) { src = wv;   dst = wkvT;   N = 768;  row_off = 768; }
  else if (z == 4) { src = wkip; dst = wkvipT; N = 768;  row_off = 0; }
  else             { src = wvip; dst = wkvipT; N = 768;  row_off = 768; }
  int c0 = blockIdx.x * 32, r0 = blockIdx.y * 32;
  if (c0 >= N || r0 >= N) return;
  int tx = threadIdx.x & 31, ty = threadIdx.x >> 5;
#pragma unroll
  for (int j = 0; j < 4; ++j)
    tile[ty + j * 8][tx] = src[(size_t)(r0 + ty + j * 8) * N + c0 + tx];
  __syncthreads();
#pragma unroll
  for (int j = 0; j < 4; ++j)
    dst[(size_t)(row_off + c0 + ty + j * 8) * N + r0 + tx] =
        f2bf(tile[tx][ty + j * 8]);
}

// ---------------------------------------------------------------------------
// 128x128 3-buffer counted-vmcnt core (kept for kv_gemm).
// ---------------------------------------------------------------------------
__device__ __forceinline__ void stage32(const short* __restrict__ gA,
                                        const short* __restrict__ gBt,
                                        int lda, int ldb, char* buf, int tid) {
#pragma unroll
  for (int li = 0; li < 2; ++li) {
    int L = li * 4096 + tid * 16;
    int row = L >> 6;
    int cb = (L & 63) ^ (((row >> 1) & 3) << 4);
    gload16(gA + (size_t)row * lda + (cb >> 1), buf + L);
    gload16(gBt + (size_t)row * ldb + (cb >> 1), buf + 8192 + L);
  }
}

__device__ __forceinline__ void compute32(const char* p0, int wr, int wc,
                                          int lr, int hk, int xr,
                                          f32x4 acc[4][4]) {
  short8 af[4], bf[4];
#pragma unroll
  for (int m = 0; m < 4; ++m) {
    int row = wr + m * 16 + lr;
    af[m] = *(const short8*)(p0 + row * 64 + (hk ^ xr));
  }
#pragma unroll
  for (int n = 0; n < 4; ++n) {
    int row = wc + n * 16 + lr;
    bf[n] = *(const short8*)(p0 + 8192 + row * 64 + (hk ^ xr));
  }
#pragma unroll
  for (int m = 0; m < 4; ++m)
#pragma unroll
    for (int n = 0; n < 4; ++n) acc[m][n] = MFMA16(af[m], bf[n], acc[m][n]);
}

template <int K>
__device__ __forceinline__ void gemm128p(
    const short* __restrict__ A, const short* __restrict__ Bt, int lda,
    int ldb, int row0, int col0, char* sm, f32x4 acc[4][4]) {
  const int tid = threadIdx.x;
  const int lane = tid & 63, wid = tid >> 6;
  const int wr = (wid >> 1) * 64, wc = (wid & 1) * 64;
  const int lr = lane & 15;
  const int hk = (lane >> 4) * 16;
  const int xr = ((lr >> 1) & 3) << 4;
  constexpr int NT = K / 32;

  const short* gA = A + (size_t)row0 * lda;
  const short* gB = Bt + (size_t)col0 * ldb;
  char* p0 = sm;
  char* p1 = sm + 16384;
  char* p2 = sm + 32768;

  stage32(gA, gB, lda, ldb, p0, tid);
  stage32(gA + 32, gB + 32, lda, ldb, p1, tid);
  asm volatile("s_waitcnt vmcnt(4)" ::: "memory");
  __builtin_amdgcn_s_barrier();

  for (int t = 0; t < NT; ++t) {
    if (t + 2 < NT)
      stage32(gA + (t + 2) * 32, gB + (t + 2) * 32, lda, ldb, p2, tid);
    __builtin_amdgcn_sched_barrier(0);
    compute32(p0, wr, wc, lr, hk, xr, acc);
    __builtin_amdgcn_sched_barrier(0);
    if (t + 2 < NT)
      asm volatile("s_waitcnt vmcnt(4)" ::: "memory");
    else
      asm volatile("s_waitcnt vmcnt(0)" ::: "memory");
    __builtin_amdgcn_s_barrier();
    char* tmp = p0; p0 = p1; p1 = p2; p2 = tmp;
  }
}

// ---------------------------------------------------------------------------
// 256x256 8-phase core (T2+T3+T4+T5). 512 threads = 8 waves (2M x 4N),
// per-wave 128x64 output, acc[8][4]. BK=64, 2 K-tiles per iteration.
// LDS 128KB: A slots [0,64K): slot*32K + mh*16K; B at 64K + same.
// A-half mh holds rows r with bit6(r)==mh (64-row interleave);
// B-half nh holds rows r with bit5(r)==nh (32-row interleave) — so each
// phase (mh,nh) reads exactly one A-half and one B-half.
// Phase: {8 A ds_reads (+4 B on nh-entry), stage 1 half-tile (2 gloads),
//   barrier, lgkmcnt(0), setprio(1), 16 MFMA, setprio(0), barrier}.
// Stage stream (iter i; u=2i,v=2i+1,w=2i+2,x=2i+3):
//   ph1:Ah1(v) ph2:Bh1(v) ph3:Bh0(w) ph4:Ah0(w) ph5:Ah1(w) ph6:Bh1(w)
//   ph7:Bh0(x) ph8:Ah0(x); vmcnt(4) at ph4/ph8 ends.
// WAR: each stage targets the half whose reads retired >=1 phase earlier
//   (phase barriers order cross-wave). RAW ledger: u's halves staged
//   <=i-1.ph6, landed by i-1.ph8's vmcnt(4) (leaves only ph7/ph8);
//   v's halves staged <=i.ph2, landed by i.ph4's vmcnt(4) (leaves ph3/ph4).
// Prologue = tile0 all + tile1 {Bh0,Ah0} (= "ph7/ph8" state), vmcnt(4).
// Tail: last iter keeps ph1/ph2 (tile NT-1 halves), skips ph3-8 stages,
//   vmcnt(0) at ph4.
// ---------------------------------------------------------------------------
template <int KTOT>
__device__ __forceinline__ void gemm256(
    const short* __restrict__ A, const short* __restrict__ Bt, int lda,
    int ldb, int row0, int col0, char* sm, f32x4 acc[8][4]) {
  const int tid = threadIdx.x;
  const int lane = tid & 63, wid = tid >> 6;
  const int wgM = wid >> 2, wgN = wid & 3;
  const int lr = lane & 15;
  const int hk = (lane >> 4) * 16;
  const int xr = (lr & 7) << 4;
  constexpr int NT = KTOT / 64;
  constexpr int NI = NT / 2;

  const short* gA = A + (size_t)row0 * lda;
  const short* gB = Bt + (size_t)col0 * ldb;

  auto stgA = [&](int tile, int h) {
#pragma unroll
    for (int p = 0; p < 2; ++p) {
      int L = p * 8192 + tid * 16;
      int hi = L >> 7, c = L & 127;
      int cb = c ^ ((hi & 7) << 4);
      int r = ((hi >> 6) << 7) | (h << 6) | (hi & 63);
      gload16(gA + (size_t)r * lda + tile * 64 + (cb >> 1),
              sm + (tile & 1) * 32768 + h * 16384 + L);
    }
  };
  auto stgB = [&](int tile, int h) {
#pragma unroll
    for (int p = 0; p < 2; ++p) {
      int L = p * 8192 + tid * 16;
      int hi = L >> 7, c = L & 127;
      int cb = c ^ ((hi & 7) << 4);
      int r = ((hi >> 5) << 6) | (h << 5) | (hi & 31);
      gload16(gB + (size_t)r * ldb + tile * 64 + (cb >> 1),
              sm + 65536 + (tile & 1) * 32768 + h * 16384 + L);
    }
  };

  short8 bf[2][2];
  auto loadA = [&](short8 af[4][2], int tile, int mh) {
    const char* a = sm + (tile & 1) * 32768 + mh * 16384;
#pragma unroll
    for (int m = 0; m < 4; ++m) {
      int hi = wgM * 64 + m * 16 + lr;
#pragma unroll
      for (int kk = 0; kk < 2; ++kk)
        af[m][kk] = *(const short8*)(a + hi * 128 + ((kk * 64 + hk) ^ xr));
    }
  };
  auto loadBf = [&](int tile, int nh) {
    const char* b = sm + 65536 + (tile & 1) * 32768 + nh * 16384;
#pragma unroll
    for (int n = 0; n < 2; ++n) {
      int hi = wgN * 32 + n * 16 + lr;
#pragma unroll
      for (int kk = 0; kk < 2; ++kk)
        bf[n][kk] = *(const short8*)(b + hi * 128 + ((kk * 64 + hk) ^ xr));
    }
  };
  auto mmac = [&](short8 af[4][2], int mh, int nh) {
    __builtin_amdgcn_s_setprio(1);
#pragma unroll
    for (int m = 0; m < 4; ++m)
#pragma unroll
      for (int n = 0; n < 2; ++n) {
        acc[mh * 4 + m][nh * 2 + n] =
            MFMA16(af[m][0], bf[n][0], acc[mh * 4 + m][nh * 2 + n]);
        acc[mh * 4 + m][nh * 2 + n] =
            MFMA16(af[m][1], bf[n][1], acc[mh * 4 + m][nh * 2 + n]);
      }
    __builtin_amdgcn_s_setprio(0);
  };

#define PH_SYNC()                                         \
  __builtin_amdgcn_s_barrier();                           \
  asm volatile("s_waitcnt lgkmcnt(0)" ::: "memory");      \
  __builtin_amdgcn_sched_barrier(0)
#define PH_END()                                          \
  __builtin_amdgcn_sched_barrier(0);                      \
  __builtin_amdgcn_s_barrier()

  // prologue
  stgB(0, 0); stgA(0, 0); stgA(0, 1); stgB(0, 1);
  stgB(1, 0); stgA(1, 0);
  asm volatile("s_waitcnt vmcnt(4)" ::: "memory");
  __builtin_amdgcn_s_barrier();

  for (int i = 0; i < NI; ++i) {
    const int u = 2 * i, v = 2 * i + 1, w = 2 * i + 2, x = 2 * i + 3;
    const bool sg = (i + 1 < NI);
    { short8 af[4][2]; loadA(af, u, 0); loadBf(u, 0); stgA(v, 1);
      PH_SYNC(); mmac(af, 0, 0); PH_END(); }                       // ph1
    { short8 af[4][2]; loadA(af, u, 1); stgB(v, 1);
      PH_SYNC(); mmac(af, 1, 0); PH_END(); }                       // ph2
    { short8 af[4][2]; loadA(af, u, 0); loadBf(u, 1); if (sg) stgB(w, 0);
      PH_SYNC(); mmac(af, 0, 1); PH_END(); }                       // ph3
    { short8 af[4][2]; loadA(af, u, 1); if (sg) stgA(w, 0);
      PH_SYNC(); mmac(af, 1, 1);
      __builtin_amdgcn_sched_barrier(0);
      if (sg) asm volatile("s_waitcnt vmcnt(4)" ::: "memory");
      else    asm volatile("s_waitcnt vmcnt(0)" ::: "memory");
      PH_END(); }                                                  // ph4
    { short8 af[4][2]; loadA(af, v, 0); loadBf(v, 0); if (sg) stgA(w, 1);
      PH_SYNC(); mmac(af, 0, 0); PH_END(); }                       // ph5
    { short8 af[4][2]; loadA(af, v, 1); if (sg) stgB(w, 1);
      PH_SYNC(); mmac(af, 1, 0); PH_END(); }                       // ph6
    { short8 af[4][2]; loadA(af, v, 0); loadBf(v, 1); if (sg) stgB(x, 0);
      PH_SYNC(); mmac(af, 0, 1); PH_END(); }                       // ph7
    { short8 af[4][2]; loadA(af, v, 1); if (sg) stgA(x, 0);
      PH_SYNC(); mmac(af, 1, 1);
      __builtin_amdgcn_sched_barrier(0);
      if (sg) asm volatile("s_waitcnt vmcnt(4)" ::: "memory");
      PH_END(); }                                                  // ph8
  }
#undef PH_SYNC
#undef PH_END
}

// 192 blocks (32 row-tiles x 6 col-tiles); XCD row-band mapping.
__device__ __forceinline__ void grid256(int& row0, int& col0) {
  int bid = blockIdx.x;  // 0..191
  int x = bid & 7, j = bid >> 3;  // j 0..23
  row0 = (x * 4 + (j & 3)) * 256;
  col0 = (j >> 2) * 256;
}

// ---------------------------------------------------------------------------
// Q projection (256x256 8-phase) + RoPE + pre-scale -> qbuf bf16 (B,H,S,64)
// ---------------------------------------------------------------------------
__global__ __launch_bounds__(512, 2) void q_proj_256(
    const short* __restrict__ hsbf, const short* __restrict__ wqT,
    const float* __restrict__ rc, const float* __restrict__ rsn,
    short* __restrict__ qbuf) {
  extern __shared__ char sm[];
  f32x4 acc[8][4] = {};
  int row0, col0;
  grid256(row0, col0);
  gemm256<1536>(hsbf, wqT, 1536, 1536, row0, col0, sm, acc);

  const int lane = threadIdx.x & 63, wid = threadIdx.x >> 6;
  const int wgM = wid >> 2, wgN = wid & 3;
  const int lr = lane & 15, lrow4 = (lane >> 4) * 4;
  const int h = (col0 + wgN * 64) >> 6;
#pragma unroll
  for (int m = 0; m < 8; ++m) {
#pragma unroll
    for (int r = 0; r < 4; ++r) {
      int grow = row0 + wgM * 128 + m * 16 + lrow4 + r;
      int b = grow >> 11, t = grow & 2047;
      float v0 = acc[m][0][r], v1 = acc[m][1][r];
      float c0 = rc[t * 32 + lr], s0 = rsn[t * 32 + lr];
      float c1 = rc[t * 32 + 16 + lr], s1 = rsn[t * 32 + 16 + lr];
      float n0 = (v0 * c0 - v1 * s0) * QK_SCALE_LOG2E;
      float n1 = (v1 * c1 + v0 * s1) * QK_SCALE_LOG2E;
      short* ob = qbuf + ((size_t)(b * 24 + h) * 2048 + t) * 64;
      ob[lr] = f2bf(n0);
      ob[16 + lr] = f2bf(n1);
      ob[32 + lr] = f2bf(acc[m][2][r] * QK_SCALE_LOG2E);
      ob[48 + lr] = f2bf(acc[m][3][r] * QK_SCALE_LOG2E);
    }
  }
}

// ---------------------------------------------------------------------------
// Output projection (256x256 8-phase) + bias + residual -> f32
// ---------------------------------------------------------------------------
__global__ __launch_bounds__(512, 2) void o_proj_256(
    const short* __restrict__ attnbf, const short* __restrict__ woT,
    const float* __restrict__ bo, const float* __restrict__ resid,
    float* __restrict__ out) {
  extern __shared__ char sm[];
  f32x4 acc[8][4] = {};
  int row0, col0;
  grid256(row0, col0);
  gemm256<1536>(attnbf, woT, 1536, 1536, row0, col0, sm, acc);

  const int lane = threadIdx.x & 63, wid = threadIdx.x >> 6;
  const int wgM = wid >> 2, wgN = wid & 3;
  const int lr = lane & 15, lrow4 = (lane >> 4) * 4;
#pragma unroll
  for (int m = 0; m < 8; ++m) {
#pragma unroll
    for (int n = 0; n < 4; ++n) {
#pragma unroll
      for (int r = 0; r < 4; ++r) {
        int grow = row0 + wgM * 128 + m * 16 + lrow4 + r;
        int gcol = col0 + wgN * 64 + n * 16 + lr;
        size_t off = (size_t)grow * 1536 + gcol;
        out[off] = acc[m][n][r] + bo[gcol] + resid[off];
      }
    }
  }
}

// ---------------------------------------------------------------------------
// Fused K|V projection GEMM (128x128 core). V^T written with the permuted
// key order so the attention P->A fragment is lane-local.
// ---------------------------------------------------------------------------
__global__ __launch_bounds__(256, 3) void kv_gemm(
    const short* __restrict__ Abf, const short* __restrict__ wkvT,
    short* __restrict__ kout, short* __restrict__ vtout, int rlog2) {
  __shared__ char sm[49152];
  f32x4 acc[4][4] = {};
  const int row0 = blockIdx.y * 128, col0 = blockIdx.x * 128;
  gemm128p<768>(Abf, wkvT, 768, 768, row0, col0, sm, acc);

  const int tid = threadIdx.x;
  const int lane = tid & 63, wid = tid >> 6;
  const int wr = (wid >> 1) * 64, wc = (wid & 1) * 64;
  const int lr = lane & 15, lrow4 = (lane >> 4) * 4;
  const int rmask = (1 << rlog2) - 1;
#pragma unroll
  for (int m = 0; m < 4; ++m) {
#pragma unroll
    for (int n = 0; n < 4; ++n) {
#pragma unroll
      for (int r = 0; r < 4; ++r) {
        int grow = row0 + wr + m * 16 + lrow4 + r;
        int gcol = col0 + wc + n * 16 + lr;
        int b = grow >> rlog2, key = grow & rmask;
        short val = f2bf(acc[m][n][r]);
        if (gcol < 768) {
          int kvh = gcol >> 6, d = gcol & 63;
          kout[((((size_t)(b * 12 + kvh)) << rlog2) + key) * 64 + d] = val;
        } else {
          int c2 = gcol - 768;
          int kvh = c2 >> 6, d = c2 & 63;
          int kp = (key & ~31) | (((key >> 2) & 3) << 3) |
                   (((key >> 4) & 1) << 2) | (key & 3);
          vtout[(((size_t)((b * 12 + kvh) * 64 + d)) << rlog2) + kp] = val;
        }
      }
    }
  }
}

// ---------------------------------------------------------------------------
// Attention (unchanged): swapped QK^T, in-register P, per-lane deferred max.
// ---------------------------------------------------------------------------
__device__ __forceinline__ void stage_tile(const short* __restrict__ ks,
                                           const short* __restrict__ vs,
                                           int vstr, short* kb, short* vb,
                                           int tid) {
#pragma unroll
  for (int q = 0; q < 2; ++q) {
    int L = q * 4096 + tid * 16;
    int row = L >> 7;
    int sc = ((L & 127) ^ ((row & 7) << 4)) >> 1;
    gload16(ks + row * 64 + sc, (char*)kb + L);
    gload16(vs + (size_t)row * vstr + sc, (char*)vb + L);
  }
}

__device__ __forceinline__ void attn_tile(const short* kb, const short* vb,
                                          const short8 qf[2],
                                          float& m_run, float& l_run,
                                          f32x4 o_acc[4], int lane) {
  const int lr = lane & 15, hi = lane >> 4;
  f32x4 s[4];
#pragma unroll
  for (int nf = 0; nf < 4; ++nf) {
    int row = nf * 16 + lr;
    int rx = (row & 7) << 4;
    const char* base = (const char*)kb + row * 128;
    short8 k0 = *(const short8*)(base + ((hi * 16) ^ rx));
    short8 k1 = *(const short8*)(base + ((64 + hi * 16) ^ rx));
    f32x4 a = {0.f, 0.f, 0.f, 0.f};
    a = MFMA16(k0, qf[0], a);
    a = MFMA16(k1, qf[1], a);
    s[nf] = a;
  }
  float mx = fmaxf(fmaxf(s[0][0], s[0][1]), fmaxf(s[0][2], s[0][3]));
#pragma unroll
  for (int nf = 1; nf < 4; ++nf)
    mx = fmaxf(mx, fmaxf(fmaxf(s[nf][0], s[nf][1]), fmaxf(s[nf][2], s[nf][3])));
  if (__any(mx - m_run > 8.0f)) {
    float mr = fmaxf(mx, __shfl_xor(mx, 16));
    mr = fmaxf(mr, __shfl_xor(mr, 32));
    float mn = fmaxf(m_run, mr);
    float corr = __builtin_amdgcn_exp2f(m_run - mn);
    m_run = mn;
    l_run *= corr;
#pragma unroll
    for (int r = 0; r < 4; ++r) {
      float cr = __shfl(corr, hi * 4 + r);
#pragma unroll
      for (int no = 0; no < 4; ++no) o_acc[no][r] *= cr;
    }
  }
  short8 pa[2];
#pragma unroll
  for (int nf = 0; nf < 4; ++nf) {
#pragma unroll
    for (int r = 0; r < 4; ++r) {
      float p = __builtin_amdgcn_exp2f(s[nf][r] - m_run);
      l_run += p;
      pa[nf >> 1][(nf & 1) * 4 + r] = f2bf_trunc(p);
    }
  }
#pragma unroll
  for (int ks = 0; ks < 2; ++ks) {
#pragma unroll
    for (int no = 0; no < 4; ++no) {
      int row = no * 16 + lr;
      int rx = (row & 7) << 4;
      short8 vf = *(const short8*)((const char*)vb + row * 128 +
                                   ((ks * 64 + hi * 16) ^ rx));
      o_acc[no] = MFMA16(pa[ks], vf, o_acc[no]);
    }
  }
}

__global__ __launch_bounds__(256, 4) void attn_kernel(
    const short* __restrict__ qbuf, const short* __restrict__ kbuf,
    const short* __restrict__ vtbuf, const short* __restrict__ kipbuf,
    const short* __restrict__ vtipbuf, short* __restrict__ attn_out) {
  const int tid = threadIdx.x;
  const int lane = tid & 63, wid = tid >> 6;
  const int f = (blockIdx.x & 7) * 384 + (blockIdx.x >> 3);
  const int qt = f & 31;
  const int h = (f >> 5) % 24;
  const int b = f / (32 * 24);
  const int kvh = h >> 1;
  const int lr = lane & 15, hi = lane >> 4;

  __shared__ short skv_k[2 * 64 * 64];
  __shared__ short skv_v[2 * 64 * 64];

  const short* qp = qbuf + (size_t)(b * 24 + h) * 2048 * 64;
  const short* kp = kbuf + (size_t)(b * 12 + kvh) * 512 * 64;
  const short* vp = vtbuf + (size_t)(b * 12 + kvh) * 64 * 512;
  const short* kip = kipbuf + (size_t)(b * 12 + kvh) * 64 * 64;
  const short* vip = vtipbuf + (size_t)(b * 12 + kvh) * 64 * 64;

  const int q0 = qt * 64 + wid * 16;
  short8 qf[2];
  qf[0] = *(const short8*)(qp + (size_t)(q0 + lr) * 64 + hi * 8);
  qf[1] = *(const short8*)(qp + (size_t)(q0 + lr) * 64 + 32 + hi * 8);

  float m1 = -1.0e30f, l1 = 0.f, m2 = -1.0e30f, l2 = 0.f;
  f32x4 oacc1[4] = {}, oacc2[4] = {};

  stage_tile(kp, vp, 512, skv_k, skv_v, tid);
  __syncthreads();

  for (int t = 0; t < 9; ++t) {
    int cur = t & 1, nxt = cur ^ 1;
    if (t < 8) {
      const short* ks_ = (t < 7) ? kp + (t + 1) * 64 * 64 : kip;
      const short* vs_ = (t < 7) ? vp + (t + 1) * 64 : vip;
      int vstr = (t < 7) ? 512 : 64;
      stage_tile(ks_, vs_, vstr, skv_k + nxt * 4096, skv_v + nxt * 4096, tid);
    }
    if (t < 8)
      attn_tile(skv_k + cur * 4096, skv_v + cur * 4096, qf, m1, l1, oacc1, lane);
    else
      attn_tile(skv_k + cur * 4096, skv_v + cur * 4096, qf, m2, l2, oacc2, lane);
    __syncthreads();
  }

  l1 += __shfl_xor(l1, 16); l1 += __shfl_xor(l1, 32);
  l2 += __shfl_xor(l2, 16); l2 += __shfl_xor(l2, 32);
  float inv1 = 1.0f / l1, inv2 = 1.0f / l2;
#pragma unroll
  for (int r = 0; r < 4; ++r) {
    float i1 = __shfl(inv1, hi * 4 + r);
    float i2 = __shfl(inv2, hi * 4 + r);
    int grow = b * 2048 + q0 + hi * 4 + r;
#pragma unroll
    for (int no = 0; no < 4; ++no) {
      float val = oacc1[no][r] * i1 + oacc2[no][r] * i2;
      attn_out[(size_t)grow * 1536 + h * 64 + no * 16 + lr] = f2bf(val);
    }
  }
}

// ---------------------------------------------------------------------------
extern "C" void kernel_launch(void* const* d_in, const int* in_sizes, int n_in,
                              void* d_out, int out_size, void* d_ws, size_t ws_size,
                              hipStream_t stream) {
  const float* hs = (const float*)d_in[0];
  const float* enc = (const float*)d_in[1];
  const float* rc = (const float*)d_in[2];
  const float* rsn = (const float*)d_in[3];
  const float* wq = (const float*)d_in[4];
  const float* wk = (const float*)d_in[5];
  const float* wv = (const float*)d_in[6];
  const float* wkip = (const float*)d_in[7];
  const float* wvip = (const float*)d_in[8];
  const float* wo = (const float*)d_in[9];
  const float* bo = (const float*)d_in[10];
  float* out = (float*)d_out;

  char* ws = (char*)d_ws;
  short* hsbf    = (short*)(ws + 0);          // 25165824 (dead after q_proj)
  short* attnbuf = (short*)(ws + 0);          // alias: written after q_proj
  short* qbuf    = (short*)(ws + 25165824);   // 25165824
  short* kbuf    = (short*)(ws + 50331648);   //  3145728
  short* vtbuf   = (short*)(ws + 53477376);   //  3145728
  short* kipbuf  = (short*)(ws + 56623104);   //   393216
  short* vtipbuf = (short*)(ws + 57016320);   //   393216
  short* textbf  = (short*)(ws + 57409536);   //  3145728
  short* ipbf    = (short*)(ws + 60555264);   //   393216
  short* wqT     = (short*)(ws + 60948480);   //  4718592
  short* woT     = (short*)(ws + 65667072);   //  4718592
  short* wkvT    = (short*)(ws + 70385664);   //  2359296
  short* wkvipT  = (short*)(ws + 72744960);   //  2359296
  // total 75104256 bytes

  hipFuncSetAttribute((const void*)q_proj_256,
                      hipFuncAttributeMaxDynamicSharedMemorySize, 131072);
  hipFuncSetAttribute((const void*)o_proj_256,
                      hipFuncAttributeMaxDynamicSharedMemorySize, 131072);

  // --- pre-pass ---
  conv_bf16_kernel<<<12288, 256, 0, stream>>>(hs, hsbf, 8192 * 1536 / 4);
  enc_pack_kernel<<<1728, 256, 0, stream>>>(enc, textbf, ipbf);
  prep_weights_kernel<<<dim3(48, 48, 6), 256, 0, stream>>>(
      wq, wo, wk, wv, wkip, wvip, wqT, woT, wkvT, wkvipT);

  // --- projections ---
  q_proj_256<<<192, 512, 131072, stream>>>(hsbf, wqT, rc, rsn, qbuf);
  kv_gemm<<<dim3(12, 16), 256, 0, stream>>>(textbf, wkvT, kbuf, vtbuf, 9);
  kv_gemm<<<dim3(12, 2), 256, 0, stream>>>(ipbf, wkvipT, kipbuf, vtipbuf, 6);

  // --- attention ---
  attn_kernel<<<3072, 256, 0, stream>>>(qbuf, kbuf, vtbuf, kipbuf,
                                        vtipbuf, attnbuf);

  // --- output projection + bias + residual ---
  o_proj_256<<<192, 512, 131072, stream>>>(attnbuf, woT, bo, hs, out);
}

// Round 16
// 188.537 us; speedup vs baseline: 1.1097x; 1.1097x over previous
//
#include <hip/hip_runtime.h>
#include <hip/hip_bf16.h>

typedef __attribute__((ext_vector_type(8))) short short8;
typedef __attribute__((ext_vector_type(4))) short short4v;
typedef __attribute__((ext_vector_type(4))) float f32x4;

#define MFMA16(a, b, c) __builtin_amdgcn_mfma_f32_16x16x32_bf16(a, b, c, 0, 0, 0)
#define QK_SCALE_LOG2E 0.18033688011112042f  // (1/8) * log2(e)

__device__ __forceinline__ short f2bf(float x) {
  union { float f; unsigned u; } v; v.f = x;
  unsigned u = v.u;
  u += 0x7FFFu + ((u >> 16) & 1u);  // RNE
  return (short)(u >> 16);
}
__device__ __forceinline__ short f2bf_trunc(float x) {
  union { float f; unsigned u; } v; v.f = x;
  return (short)(v.u >> 16);
}

__device__ __forceinline__ void gload16(const void* g, void* l) {
  __builtin_amdgcn_global_load_lds(
      (const __attribute__((address_space(1))) unsigned int*)g,
      (__attribute__((address_space(3))) unsigned int*)l, 16, 0, 0);
}

// ---------------------------------------------------------------------------
// Pre-pass kernels
// ---------------------------------------------------------------------------
// enc (4 x 576 x 768 f32) -> text_bf (4*512 x 768) + ip_bf (4*64 x 768)
__global__ __launch_bounds__(256) void enc_pack_kernel(
    const float* __restrict__ enc, short* __restrict__ text,
    short* __restrict__ ip) {
  int i4 = blockIdx.x * 256 + threadIdx.x;
  int i = i4 * 4;
  if (i >= 4 * 576 * 768) return;
  int c = i % 768;
  int rs = i / 768;
  int b = rs / 576, s = rs % 576;
  f32x4 v = *(const f32x4*)(enc + i);
  short4v o;
  o[0] = f2bf(v[0]); o[1] = f2bf(v[1]); o[2] = f2bf(v[2]); o[3] = f2bf(v[3]);
  if (s < 512)
    *(short4v*)(text + (size_t)(b * 512 + s) * 768 + c) = o;
  else
    *(short4v*)(ip + (size_t)(b * 64 + (s - 512)) * 768 + c) = o;
}

// All weight transposes fused -> (N x K) bf16 row-major.
__global__ __launch_bounds__(256) void prep_weights_kernel(
    const float* __restrict__ wq, const float* __restrict__ wo,
    const float* __restrict__ wk, const float* __restrict__ wv,
    const float* __restrict__ wkip, const float* __restrict__ wvip,
    short* __restrict__ wqT, short* __restrict__ woT,
    short* __restrict__ wkvT, short* __restrict__ wkvipT) {
  __shared__ float tile[32][33];
  const int z = blockIdx.z;
  const float* src; short* dst; int N, row_off;
  if (z == 0)      { src = wq;   dst = wqT;    N = 1536; row_off = 0; }
  else if (z == 1) { src = wo;   dst = woT;    N = 1536; row_off = 0; }
  else if (z == 2) { src = wk;   dst = wkvT;   N = 768;  row_off = 0; }
  else if (z == 3) { src = wv;   dst = wkvT;   N = 768;  row_off = 768; }
  else if (z == 4) { src = wkip; dst = wkvipT; N = 768;  row_off = 0; }
  else             { src = wvip; dst = wkvipT; N = 768;  row_off = 768; }
  int c0 = blockIdx.x * 32, r0 = blockIdx.y * 32;
  if (c0 >= N || r0 >= N) return;
  int tx = threadIdx.x & 31, ty = threadIdx.x >> 5;
#pragma unroll
  for (int j = 0; j < 4; ++j)
    tile[ty + j * 8][tx] = src[(size_t)(r0 + ty + j * 8) * N + c0 + tx];
  __syncthreads();
#pragma unroll
  for (int j = 0; j < 4; ++j)
    dst[(size_t)(row_off + c0 + ty + j * 8) * N + r0 + tx] =
        f2bf(tile[tx][ty + j * 8]);
}

// ---------------------------------------------------------------------------
// 128x128-tile, BK=32, 3-buffer counted-vmcnt GEMM core.
// Swizzle f(row)=((row>>1)&3)<<4 on both sides; 48 KB LDS -> 3 blocks/CU.
// ---------------------------------------------------------------------------
__device__ __forceinline__ void stage32(const short* __restrict__ gA,
                                        const short* __restrict__ gBt,
                                        int lda, int ldb, char* buf, int tid) {
#pragma unroll
  for (int li = 0; li < 2; ++li) {
    int L = li * 4096 + tid * 16;
    int row = L >> 6;
    int cb = (L & 63) ^ (((row >> 1) & 3) << 4);
    gload16(gA + (size_t)row * lda + (cb >> 1), buf + L);
    gload16(gBt + (size_t)row * ldb + (cb >> 1), buf + 8192 + L);
  }
}

__device__ __forceinline__ void compute32(const char* p0, int wr, int wc,
                                          int lr, int hk, int xr,
                                          f32x4 acc[4][4]) {
  short8 af[4], bf[4];
#pragma unroll
  for (int m = 0; m < 4; ++m) {
    int row = wr + m * 16 + lr;
    af[m] = *(const short8*)(p0 + row * 64 + (hk ^ xr));
  }
#pragma unroll
  for (int n = 0; n < 4; ++n) {
    int row = wc + n * 16 + lr;
    bf[n] = *(const short8*)(p0 + 8192 + row * 64 + (hk ^ xr));
  }
#pragma unroll
  for (int m = 0; m < 4; ++m)
#pragma unroll
    for (int n = 0; n < 4; ++n) acc[m][n] = MFMA16(af[m], bf[n], acc[m][n]);
}

template <int K>
__device__ __forceinline__ void gemm128p(
    const short* __restrict__ A, const short* __restrict__ Bt, int lda,
    int ldb, int row0, int col0, char* sm, f32x4 acc[4][4]) {
  const int tid = threadIdx.x;
  const int lane = tid & 63, wid = tid >> 6;
  const int wr = (wid >> 1) * 64, wc = (wid & 1) * 64;
  const int lr = lane & 15;
  const int hk = (lane >> 4) * 16;
  const int xr = ((lr >> 1) & 3) << 4;
  constexpr int NT = K / 32;

  const short* gA = A + (size_t)row0 * lda;
  const short* gB = Bt + (size_t)col0 * ldb;
  char* p0 = sm;
  char* p1 = sm + 16384;
  char* p2 = sm + 32768;

  stage32(gA, gB, lda, ldb, p0, tid);
  stage32(gA + 32, gB + 32, lda, ldb, p1, tid);
  asm volatile("s_waitcnt vmcnt(4)" ::: "memory");
  __builtin_amdgcn_s_barrier();

  for (int t = 0; t < NT; ++t) {
    if (t + 2 < NT)
      stage32(gA + (t + 2) * 32, gB + (t + 2) * 32, lda, ldb, p2, tid);
    __builtin_amdgcn_sched_barrier(0);
    compute32(p0, wr, wc, lr, hk, xr, acc);
    __builtin_amdgcn_sched_barrier(0);
    if (t + 2 < NT)
      asm volatile("s_waitcnt vmcnt(4)" ::: "memory");
    else
      asm volatile("s_waitcnt vmcnt(0)" ::: "memory");
    __builtin_amdgcn_s_barrier();
    char* tmp = p0; p0 = p1; p1 = p2; p2 = tmp;
  }
}

// Row-band XCD grid mapping for 768 blocks (64 row-panels x 12 col-panels).
__device__ __forceinline__ void grid128(int& row0, int& col0) {
  int bid = blockIdx.x;  // 0..767
  int x = bid & 7;
  int j = bid >> 3;      // 0..95
  row0 = (x * 8 + (j & 7)) * 128;
  col0 = (j >> 3) * 128;
}

// ---------------------------------------------------------------------------
// Q projection with FUSED f32->bf16 A-staging (reads hs f32 directly).
// Ledger: per tile t issues Af32(t+2) 4, B(t+2) 2. End-of-tile vmcnt(6)
// leaves exactly those 6 in flight -> A(t+1) regs + B(t+1) LDS landed.
// ---------------------------------------------------------------------------
__device__ __forceinline__ void q_issueA(const float* __restrict__ gAf,
                                         int tid, f32x4 ar[4]) {
#pragma unroll
  for (int li = 0; li < 2; ++li) {
    int L = li * 4096 + tid * 16;
    int row = L >> 6;
    int cb = (L & 63) ^ (((row >> 1) & 3) << 4);
    const float* src = gAf + (size_t)row * 1536 + (cb >> 1);
    ar[li * 2] = *(const f32x4*)src;
    ar[li * 2 + 1] = *(const f32x4*)(src + 4);
  }
}
__device__ __forceinline__ void q_writeA(char* buf, int tid, const f32x4 ar[4]) {
#pragma unroll
  for (int li = 0; li < 2; ++li) {
    int L = li * 4096 + tid * 16;
    short8 s;
#pragma unroll
    for (int j = 0; j < 4; ++j) {
      s[j] = f2bf_trunc(ar[li * 2][j]);
      s[j + 4] = f2bf_trunc(ar[li * 2 + 1][j]);
    }
    *(short8*)(buf + L) = s;
  }
}
__device__ __forceinline__ void q_stageB(const short* __restrict__ gBt,
                                         char* buf, int tid) {
#pragma unroll
  for (int li = 0; li < 2; ++li) {
    int L = li * 4096 + tid * 16;
    int row = L >> 6;
    int cb = (L & 63) ^ (((row >> 1) & 3) << 4);
    gload16(gBt + (size_t)row * 1536 + (cb >> 1), buf + 8192 + L);
  }
}

__global__ __launch_bounds__(256, 3) void q_proj_128p(
    const float* __restrict__ hs, const short* __restrict__ wqT,
    const float* __restrict__ rc, const float* __restrict__ rsn,
    short* __restrict__ qbuf) {
  __shared__ char sm[49152];
  f32x4 acc[4][4] = {};
  int row0, col0;
  grid128(row0, col0);

  const int tid = threadIdx.x;
  const int lane = tid & 63, wid = tid >> 6;
  const int wr = (wid >> 1) * 64, wc = (wid & 1) * 64;
  const int lr = lane & 15;
  const int hk = (lane >> 4) * 16;
  const int xr = ((lr >> 1) & 3) << 4;
  constexpr int NT = 48;

  const float* gAf = hs + (size_t)row0 * 1536;
  const short* gB = wqT + (size_t)col0 * 1536;
  char* p0 = sm;
  char* p1 = sm + 16384;
  char* p2 = sm + 32768;
  f32x4 arA[4], arB[4];

  q_issueA(gAf, tid, arA);
  q_stageB(gB, p0, tid);
  q_issueA(gAf + 32, tid, arB);
  q_stageB(gB + 32, p1, tid);
  asm volatile("s_waitcnt vmcnt(8)" ::: "memory");  // A0 landed
  q_writeA(p0, tid, arA);
  asm volatile("s_waitcnt vmcnt(6) lgkmcnt(0)" ::: "memory");  // B0 + write vis
  __builtin_amdgcn_s_barrier();

  for (int t = 0; t < NT; ++t) {
    if (t + 2 < NT) {
      if ((t & 1) == 0) q_issueA(gAf + (t + 2) * 32, tid, arA);
      else              q_issueA(gAf + (t + 2) * 32, tid, arB);
      q_stageB(gB + (t + 2) * 32, p2, tid);
    }
    __builtin_amdgcn_sched_barrier(0);
    compute32(p0, wr, wc, lr, hk, xr, acc);
    __builtin_amdgcn_sched_barrier(0);
    if (t + 2 < NT)
      asm volatile("s_waitcnt vmcnt(6)" ::: "memory");  // A(t+1),B(t+1) landed
    else
      asm volatile("s_waitcnt vmcnt(0)" ::: "memory");
    if (t + 1 < NT) {
      if ((t & 1) == 0) q_writeA(p1, tid, arB);
      else              q_writeA(p1, tid, arA);
    }
    asm volatile("s_waitcnt lgkmcnt(0)" ::: "memory");
    __builtin_amdgcn_s_barrier();
    char* tmp = p0; p0 = p1; p1 = p2; p2 = tmp;
  }

  // epilogue: RoPE + pre-scale, write qbuf (B,H,S,64)
  const int lrow4 = (lane >> 4) * 4;
  const int h = (col0 + wc) >> 6;
#pragma unroll
  for (int m = 0; m < 4; ++m) {
#pragma unroll
    for (int r = 0; r < 4; ++r) {
      int grow = row0 + wr + m * 16 + lrow4 + r;
      int b = grow >> 11, t = grow & 2047;
      float v0 = acc[m][0][r], v1 = acc[m][1][r];
      float c0 = rc[t * 32 + lr], s0 = rsn[t * 32 + lr];
      float c1 = rc[t * 32 + 16 + lr], s1 = rsn[t * 32 + 16 + lr];
      float n0 = (v0 * c0 - v1 * s0) * QK_SCALE_LOG2E;
      float n1 = (v1 * c1 + v0 * s1) * QK_SCALE_LOG2E;
      short* ob = qbuf + ((size_t)(b * 24 + h) * 2048 + t) * 64;
      ob[lr] = f2bf(n0);
      ob[16 + lr] = f2bf(n1);
      ob[32 + lr] = f2bf(acc[m][2][r] * QK_SCALE_LOG2E);
      ob[48 + lr] = f2bf(acc[m][3][r] * QK_SCALE_LOG2E);
    }
  }
}

// ---------------------------------------------------------------------------
// Output projection: 3-buffer LDS core + plain bias/resid epilogue.
// ---------------------------------------------------------------------------
__global__ __launch_bounds__(256, 3) void o_proj_128p(
    const short* __restrict__ attnbf, const short* __restrict__ woT,
    const float* __restrict__ bo, const float* __restrict__ resid,
    float* __restrict__ out) {
  __shared__ char sm[49152];
  f32x4 acc[4][4] = {};
  int row0, col0;
  grid128(row0, col0);
  gemm128p<1536>(attnbf, woT, 1536, 1536, row0, col0, sm, acc);

  const int lane = threadIdx.x & 63, wid = threadIdx.x >> 6;
  const int wr = (wid >> 1) * 64, wc = (wid & 1) * 64;
  const int lr = lane & 15, lrow4 = (lane >> 4) * 4;
#pragma unroll
  for (int m = 0; m < 4; ++m) {
#pragma unroll
    for (int n = 0; n < 4; ++n) {
#pragma unroll
      for (int r = 0; r < 4; ++r) {
        int grow = row0 + wr + m * 16 + lrow4 + r;
        int gcol = col0 + wc + n * 16 + lr;
        size_t off = (size_t)grow * 1536 + gcol;
        out[off] = acc[m][n][r] + bo[gcol] + resid[off];
      }
    }
  }
}

// ---------------------------------------------------------------------------
// Fused K|V projection GEMM — SINGLE launch covering text (y<16) and ip
// (y>=16). V^T written with the permuted key order so the attention P->A
// fragment is lane-local:
//   col = (key & ~31) | ((key>>2)&3)<<3 | ((key>>4)&1)<<2 | (key&3)
// ---------------------------------------------------------------------------
__global__ __launch_bounds__(256, 3) void kv_gemm_all(
    const short* __restrict__ textbf, const short* __restrict__ ipbf,
    const short* __restrict__ wkvT, const short* __restrict__ wkvipT,
    short* __restrict__ kbuf, short* __restrict__ vtbuf,
    short* __restrict__ kipbuf, short* __restrict__ vtipbuf) {
  __shared__ char sm[49152];
  f32x4 acc[4][4] = {};
  const bool ip = blockIdx.y >= 16;
  const short* Abf = ip ? ipbf : textbf;
  const short* W = ip ? wkvipT : wkvT;
  short* kout = ip ? kipbuf : kbuf;
  short* vtout = ip ? vtipbuf : vtbuf;
  const int rlog2 = ip ? 6 : 9;
  const int row0 = (ip ? (blockIdx.y - 16) : blockIdx.y) * 128;
  const int col0 = blockIdx.x * 128;
  gemm128p<768>(Abf, W, 768, 768, row0, col0, sm, acc);

  const int tid = threadIdx.x;
  const int lane = tid & 63, wid = tid >> 6;
  const int wr = (wid >> 1) * 64, wc = (wid & 1) * 64;
  const int lr = lane & 15, lrow4 = (lane >> 4) * 4;
  const int rmask = (1 << rlog2) - 1;
#pragma unroll
  for (int m = 0; m < 4; ++m) {
#pragma unroll
    for (int n = 0; n < 4; ++n) {
#pragma unroll
      for (int r = 0; r < 4; ++r) {
        int grow = row0 + wr + m * 16 + lrow4 + r;
        int gcol = col0 + wc + n * 16 + lr;
        int b = grow >> rlog2, key = grow & rmask;
        short val = f2bf(acc[m][n][r]);
        if (gcol < 768) {
          int kvh = gcol >> 6, d = gcol & 63;
          kout[((((size_t)(b * 12 + kvh)) << rlog2) + key) * 64 + d] = val;
        } else {
          int c2 = gcol - 768;
          int kvh = c2 >> 6, d = c2 & 63;
          int kp = (key & ~31) | (((key >> 2) & 3) << 3) |
                   (((key >> 4) & 1) << 2) | (key & 3);
          vtout[(((size_t)((b * 12 + kvh) * 64 + d)) << rlog2) + kp] = val;
        }
      }
    }
  }
}

// ---------------------------------------------------------------------------
// Attention: swapped QK^T, in-register P, per-lane deferred max — now with a
// 3-buffer counted-vmcnt K/V pipeline (same ledger as gemm128p):
//   prologue: stage t0->b0, t1->b1 (8 outstanding); vmcnt(4); barrier.
//   tile t: stage t+2 -> b[(t+2)%3]; compute b[t%3];
//           t+2<=8 -> vmcnt(4) [t+1 landed, t+2 in flight];
//           t==7   -> vmcnt(0) [tile 8 staged at t=6 must land];
//           barrier (WAR: stage target = buffer read at t-1, retired).
// Per-thread loads/tile = 4 (2 K + 2 V). LDS 48KB -> 3 blocks/CU.
// ---------------------------------------------------------------------------
__device__ __forceinline__ void stage_tile(const short* __restrict__ ks,
                                           const short* __restrict__ vs,
                                           int vstr, short* kb, short* vb,
                                           int tid) {
#pragma unroll
  for (int q = 0; q < 2; ++q) {
    int L = q * 4096 + tid * 16;
    int row = L >> 7;
    int sc = ((L & 127) ^ ((row & 7) << 4)) >> 1;
    gload16(ks + row * 64 + sc, (char*)kb + L);
    gload16(vs + (size_t)row * vstr + sc, (char*)vb + L);
  }
}

__device__ __forceinline__ void attn_tile(const short* kb, const short* vb,
                                          const short8 qf[2],
                                          float& m_run, float& l_run,
                                          f32x4 o_acc[4], int lane) {
  const int lr = lane & 15, hi = lane >> 4;
  f32x4 s[4];
#pragma unroll
  for (int nf = 0; nf < 4; ++nf) {
    int row = nf * 16 + lr;
    int rx = (row & 7) << 4;
    const char* base = (const char*)kb + row * 128;
    short8 k0 = *(const short8*)(base + ((hi * 16) ^ rx));
    short8 k1 = *(const short8*)(base + ((64 + hi * 16) ^ rx));
    f32x4 a = {0.f, 0.f, 0.f, 0.f};
    a = MFMA16(k0, qf[0], a);
    a = MFMA16(k1, qf[1], a);
    s[nf] = a;
  }
  float mx = fmaxf(fmaxf(s[0][0], s[0][1]), fmaxf(s[0][2], s[0][3]));
#pragma unroll
  for (int nf = 1; nf < 4; ++nf)
    mx = fmaxf(mx, fmaxf(fmaxf(s[nf][0], s[nf][1]), fmaxf(s[nf][2], s[nf][3])));
  if (__any(mx - m_run > 8.0f)) {
    float mr = fmaxf(mx, __shfl_xor(mx, 16));
    mr = fmaxf(mr, __shfl_xor(mr, 32));
    float mn = fmaxf(m_run, mr);
    float corr = __builtin_amdgcn_exp2f(m_run - mn);
    m_run = mn;
    l_run *= corr;
#pragma unroll
    for (int r = 0; r < 4; ++r) {
      float cr = __shfl(corr, hi * 4 + r);
#pragma unroll
      for (int no = 0; no < 4; ++no) o_acc[no][r] *= cr;
    }
  }
  short8 pa[2];
#pragma unroll
  for (int nf = 0; nf < 4; ++nf) {
#pragma unroll
    for (int r = 0; r < 4; ++r) {
      float p = __builtin_amdgcn_exp2f(s[nf][r] - m_run);
      l_run += p;
      pa[nf >> 1][(nf & 1) * 4 + r] = f2bf_trunc(p);
    }
  }
#pragma unroll
  for (int ks = 0; ks < 2; ++ks) {
#pragma unroll
    for (int no = 0; no < 4; ++no) {
      int row = no * 16 + lr;
      int rx = (row & 7) << 4;
      short8 vf = *(const short8*)((const char*)vb + row * 128 +
                                   ((ks * 64 + hi * 16) ^ rx));
      o_acc[no] = MFMA16(pa[ks], vf, o_acc[no]);
    }
  }
}

__global__ __launch_bounds__(256, 3) void attn_kernel(
    const short* __restrict__ qbuf, const short* __restrict__ kbuf,
    const short* __restrict__ vtbuf, const short* __restrict__ kipbuf,
    const short* __restrict__ vtipbuf, short* __restrict__ attn_out) {
  const int tid = threadIdx.x;
  const int lane = tid & 63, wid = tid >> 6;
  const int f = (blockIdx.x & 7) * 384 + (blockIdx.x >> 3);
  const int qt = f & 31;
  const int h = (f >> 5) % 24;
  const int b = f / (32 * 24);
  const int kvh = h >> 1;
  const int lr = lane & 15, hi = lane >> 4;

  __shared__ short skv_k[3 * 64 * 64];
  __shared__ short skv_v[3 * 64 * 64];

  const short* qp = qbuf + (size_t)(b * 24 + h) * 2048 * 64;
  const short* kp = kbuf + (size_t)(b * 12 + kvh) * 512 * 64;
  const short* vp = vtbuf + (size_t)(b * 12 + kvh) * 64 * 512;
  const short* kip = kipbuf + (size_t)(b * 12 + kvh) * 64 * 64;
  const short* vip = vtipbuf + (size_t)(b * 12 + kvh) * 64 * 64;

  const int q0 = qt * 64 + wid * 16;
  short8 qf[2];
  qf[0] = *(const short8*)(qp + (size_t)(q0 + lr) * 64 + hi * 8);
  qf[1] = *(const short8*)(qp + (size_t)(q0 + lr) * 64 + 32 + hi * 8);

  float m1 = -1.0e30f, l1 = 0.f, m2 = -1.0e30f, l2 = 0.f;
  f32x4 oacc1[4] = {}, oacc2[4] = {};

  // tile sources: 0..7 text, 8 = ip
  stage_tile(kp, vp, 512, skv_k, skv_v, tid);
  stage_tile(kp + 64 * 64, vp + 64, 512, skv_k + 4096, skv_v + 4096, tid);
  asm volatile("s_waitcnt vmcnt(4)" ::: "memory");
  __builtin_amdgcn_s_barrier();

  for (int t = 0; t < 9; ++t) {
    if (t + 2 <= 8) {
      int tt = t + 2;
      const short* ks_ = (tt < 8) ? kp + tt * 64 * 64 : kip;
      const short* vs_ = (tt < 8) ? vp + tt * 64 : vip;
      int vstr = (tt < 8) ? 512 : 64;
      int bsel = tt % 3;
      stage_tile(ks_, vs_, vstr, skv_k + bsel * 4096, skv_v + bsel * 4096, tid);
    }
    __builtin_amdgcn_sched_barrier(0);
    int cur = t % 3;
    if (t < 8)
      attn_tile(skv_k + cur * 4096, skv_v + cur * 4096, qf, m1, l1, oacc1, lane);
    else
      attn_tile(skv_k + cur * 4096, skv_v + cur * 4096, qf, m2, l2, oacc2, lane);
    __builtin_amdgcn_sched_barrier(0);
    if (t + 2 <= 8)
      asm volatile("s_waitcnt vmcnt(4)" ::: "memory");
    else if (t + 1 <= 8)
      asm volatile("s_waitcnt vmcnt(0)" ::: "memory");
    __builtin_amdgcn_s_barrier();
  }

  l1 += __shfl_xor(l1, 16); l1 += __shfl_xor(l1, 32);
  l2 += __shfl_xor(l2, 16); l2 += __shfl_xor(l2, 32);
  float inv1 = 1.0f / l1, inv2 = 1.0f / l2;
#pragma unroll
  for (int r = 0; r < 4; ++r) {
    float i1 = __shfl(inv1, hi * 4 + r);
    float i2 = __shfl(inv2, hi * 4 + r);
    int grow = b * 2048 + q0 + hi * 4 + r;
#pragma unroll
    for (int no = 0; no < 4; ++no) {
      float val = oacc1[no][r] * i1 + oacc2[no][r] * i2;
      attn_out[(size_t)grow * 1536 + h * 64 + no * 16 + lr] = f2bf(val);
    }
  }
}

// ---------------------------------------------------------------------------
extern "C" void kernel_launch(void* const* d_in, const int* in_sizes, int n_in,
                              void* d_out, int out_size, void* d_ws, size_t ws_size,
                              hipStream_t stream) {
  const float* hs = (const float*)d_in[0];
  const float* enc = (const float*)d_in[1];
  const float* rc = (const float*)d_in[2];
  const float* rsn = (const float*)d_in[3];
  const float* wq = (const float*)d_in[4];
  const float* wk = (const float*)d_in[5];
  const float* wv = (const float*)d_in[6];
  const float* wkip = (const float*)d_in[7];
  const float* wvip = (const float*)d_in[8];
  const float* wo = (const float*)d_in[9];
  const float* bo = (const float*)d_in[10];
  float* out = (float*)d_out;

  char* ws = (char*)d_ws;
  short* attnbuf = (short*)(ws + 0);          // 25165824
  short* qbuf    = (short*)(ws + 25165824);   // 25165824
  short* kbuf    = (short*)(ws + 50331648);   //  3145728
  short* vtbuf   = (short*)(ws + 53477376);   //  3145728
  short* kipbuf  = (short*)(ws + 56623104);   //   393216
  short* vtipbuf = (short*)(ws + 57016320);   //   393216
  short* textbf  = (short*)(ws + 57409536);   //  3145728
  short* ipbf    = (short*)(ws + 60555264);   //   393216
  short* wqT     = (short*)(ws + 60948480);   //  4718592
  short* woT     = (short*)(ws + 65667072);   //  4718592
  short* wkvT    = (short*)(ws + 70385664);   //  2359296
  short* wkvipT  = (short*)(ws + 72744960);   //  2359296
  // total 75104256 bytes

  // --- pre-pass: pack/transpose weights + enc to bf16 ---
  enc_pack_kernel<<<1728, 256, 0, stream>>>(enc, textbf, ipbf);
  prep_weights_kernel<<<dim3(48, 48, 6), 256, 0, stream>>>(
      wq, wo, wk, wv, wkip, wvip, wqT, woT, wkvT, wkvipT);

  // --- projections ---
  q_proj_128p<<<768, 256, 0, stream>>>(hs, wqT, rc, rsn, qbuf);
  kv_gemm_all<<<dim3(12, 18), 256, 0, stream>>>(textbf, ipbf, wkvT, wkvipT,
                                                kbuf, vtbuf, kipbuf, vtipbuf);

  // --- attention ---
  attn_kernel<<<3072, 256, 0, stream>>>(qbuf, kbuf, vtbuf, kipbuf,
                                        vtipbuf, attnbuf);

  // --- output projection + bias + residual ---
  o_proj_128p<<<768, 256, 0, stream>>>(attnbuf, woT, bo, hs, out);
}

// Round 17
// 178.540 us; speedup vs baseline: 1.1718x; 1.0560x over previous
//
#include <hip/hip_runtime.h>
#include <hip/hip_bf16.h>

typedef __attribute__((ext_vector_type(8))) short short8;
typedef __attribute__((ext_vector_type(4))) short short4v;
typedef __attribute__((ext_vector_type(4))) float f32x4;

#define MFMA16(a, b, c) __builtin_amdgcn_mfma_f32_16x16x32_bf16(a, b, c, 0, 0, 0)
#define QK_SCALE_LOG2E 0.18033688011112042f  // (1/8) * log2(e)

__device__ __forceinline__ short f2bf(float x) {
  union { float f; unsigned u; } v; v.f = x;
  unsigned u = v.u;
  u += 0x7FFFu + ((u >> 16) & 1u);  // RNE
  return (short)(u >> 16);
}
__device__ __forceinline__ short f2bf_trunc(float x) {
  union { float f; unsigned u; } v; v.f = x;
  return (short)(v.u >> 16);
}

__device__ __forceinline__ void gload16(const void* g, void* l) {
  __builtin_amdgcn_global_load_lds(
      (const __attribute__((address_space(1))) unsigned int*)g,
      (__attribute__((address_space(3))) unsigned int*)l, 16, 0, 0);
}

// ---------------------------------------------------------------------------
// Fused pre-pass: blocks [0,1728) = enc pack; [1728,4032) = wq transpose;
// [4032,6336) = wo transpose; [6336,8640) = wk/wv/wkip/wvip (576 each).
// All outputs (N x K) bf16 row-major.
// ---------------------------------------------------------------------------
__global__ __launch_bounds__(256) void prepass_kernel(
    const float* __restrict__ enc, short* __restrict__ text,
    short* __restrict__ ip,
    const float* __restrict__ wq, const float* __restrict__ wo,
    const float* __restrict__ wk, const float* __restrict__ wv,
    const float* __restrict__ wkip, const float* __restrict__ wvip,
    short* __restrict__ wqT, short* __restrict__ woT,
    short* __restrict__ wkvT, short* __restrict__ wkvipT) {
  __shared__ float tile[32][33];
  int bid = blockIdx.x;
  if (bid < 1728) {
    int i4 = bid * 256 + threadIdx.x;
    int i = i4 * 4;
    if (i >= 4 * 576 * 768) return;
    int c = i % 768;
    int rs = i / 768;
    int b = rs / 576, s = rs % 576;
    f32x4 v = *(const f32x4*)(enc + i);
    short4v o;
    o[0] = f2bf(v[0]); o[1] = f2bf(v[1]); o[2] = f2bf(v[2]); o[3] = f2bf(v[3]);
    if (s < 512)
      *(short4v*)(text + (size_t)(b * 512 + s) * 768 + c) = o;
    else
      *(short4v*)(ip + (size_t)(b * 64 + (s - 512)) * 768 + c) = o;
    return;
  }
  bid -= 1728;
  const float* src; short* dst; int N, row_off, c0, r0;
  if (bid < 2304) {
    src = wq; dst = wqT; N = 1536; row_off = 0;
    c0 = (bid % 48) * 32; r0 = (bid / 48) * 32;
  } else if (bid < 4608) {
    bid -= 2304;
    src = wo; dst = woT; N = 1536; row_off = 0;
    c0 = (bid % 48) * 32; r0 = (bid / 48) * 32;
  } else {
    bid -= 4608;
    int z = bid / 576; bid %= 576;
    N = 768;
    if (z == 0)      { src = wk;   dst = wkvT;   row_off = 0; }
    else if (z == 1) { src = wv;   dst = wkvT;   row_off = 768; }
    else if (z == 2) { src = wkip; dst = wkvipT; row_off = 0; }
    else             { src = wvip; dst = wkvipT; row_off = 768; }
    c0 = (bid % 24) * 32; r0 = (bid / 24) * 32;
  }
  int tx = threadIdx.x & 31, ty = threadIdx.x >> 5;
#pragma unroll
  for (int j = 0; j < 4; ++j)
    tile[ty + j * 8][tx] = src[(size_t)(r0 + ty + j * 8) * N + c0 + tx];
  __syncthreads();
#pragma unroll
  for (int j = 0; j < 4; ++j)
    dst[(size_t)(row_off + c0 + ty + j * 8) * N + r0 + tx] =
        f2bf(tile[tx][ty + j * 8]);
}

// ---------------------------------------------------------------------------
// 128x128-tile, BK=32, 3-buffer counted-vmcnt GEMM core.
// Swizzle f(row)=((row>>1)&3)<<4 on both sides; 48 KB LDS -> 3 blocks/CU.
// ---------------------------------------------------------------------------
__device__ __forceinline__ void stage32(const short* __restrict__ gA,
                                        const short* __restrict__ gBt,
                                        int lda, int ldb, char* buf, int tid) {
#pragma unroll
  for (int li = 0; li < 2; ++li) {
    int L = li * 4096 + tid * 16;
    int row = L >> 6;
    int cb = (L & 63) ^ (((row >> 1) & 3) << 4);
    gload16(gA + (size_t)row * lda + (cb >> 1), buf + L);
    gload16(gBt + (size_t)row * ldb + (cb >> 1), buf + 8192 + L);
  }
}

__device__ __forceinline__ void compute32(const char* p0, int wr, int wc,
                                          int lr, int hk, int xr,
                                          f32x4 acc[4][4]) {
  short8 af[4], bf[4];
#pragma unroll
  for (int m = 0; m < 4; ++m) {
    int row = wr + m * 16 + lr;
    af[m] = *(const short8*)(p0 + row * 64 + (hk ^ xr));
  }
#pragma unroll
  for (int n = 0; n < 4; ++n) {
    int row = wc + n * 16 + lr;
    bf[n] = *(const short8*)(p0 + 8192 + row * 64 + (hk ^ xr));
  }
#pragma unroll
  for (int m = 0; m < 4; ++m)
#pragma unroll
    for (int n = 0; n < 4; ++n) acc[m][n] = MFMA16(af[m], bf[n], acc[m][n]);
}

template <int K>
__device__ __forceinline__ void gemm128p(
    const short* __restrict__ A, const short* __restrict__ Bt, int lda,
    int ldb, int row0, int col0, char* sm, f32x4 acc[4][4]) {
  const int tid = threadIdx.x;
  const int lane = tid & 63, wid = tid >> 6;
  const int wr = (wid >> 1) * 64, wc = (wid & 1) * 64;
  const int lr = lane & 15;
  const int hk = (lane >> 4) * 16;
  const int xr = ((lr >> 1) & 3) << 4;
  constexpr int NT = K / 32;

  const short* gA = A + (size_t)row0 * lda;
  const short* gB = Bt + (size_t)col0 * ldb;
  char* p0 = sm;
  char* p1 = sm + 16384;
  char* p2 = sm + 32768;

  stage32(gA, gB, lda, ldb, p0, tid);
  stage32(gA + 32, gB + 32, lda, ldb, p1, tid);
  asm volatile("s_waitcnt vmcnt(4)" ::: "memory");
  __builtin_amdgcn_s_barrier();

  for (int t = 0; t < NT; ++t) {
    if (t + 2 < NT)
      stage32(gA + (t + 2) * 32, gB + (t + 2) * 32, lda, ldb, p2, tid);
    __builtin_amdgcn_sched_barrier(0);
    compute32(p0, wr, wc, lr, hk, xr, acc);
    __builtin_amdgcn_sched_barrier(0);
    if (t + 2 < NT)
      asm volatile("s_waitcnt vmcnt(4)" ::: "memory");
    else
      asm volatile("s_waitcnt vmcnt(0)" ::: "memory");
    __builtin_amdgcn_s_barrier();
    char* tmp = p0; p0 = p1; p1 = p2; p2 = tmp;
  }
}

// Row-band XCD grid mapping for 768 blocks (64 row-panels x 12 col-panels).
__device__ __forceinline__ void grid128(int bid, int& row0, int& col0) {
  int x = bid & 7;
  int j = bid >> 3;      // 0..95
  row0 = (x * 8 + (j & 7)) * 128;
  col0 = (j >> 3) * 128;
}

// ---------------------------------------------------------------------------
// Q projection body (fused f32->bf16 A-staging; see R14 ledger).
// ---------------------------------------------------------------------------
__device__ __forceinline__ void q_issueA(const float* __restrict__ gAf,
                                         int tid, f32x4 ar[4]) {
#pragma unroll
  for (int li = 0; li < 2; ++li) {
    int L = li * 4096 + tid * 16;
    int row = L >> 6;
    int cb = (L & 63) ^ (((row >> 1) & 3) << 4);
    const float* src = gAf + (size_t)row * 1536 + (cb >> 1);
    ar[li * 2] = *(const f32x4*)src;
    ar[li * 2 + 1] = *(const f32x4*)(src + 4);
  }
}
__device__ __forceinline__ void q_writeA(char* buf, int tid, const f32x4 ar[4]) {
#pragma unroll
  for (int li = 0; li < 2; ++li) {
    int L = li * 4096 + tid * 16;
    short8 s;
#pragma unroll
    for (int j = 0; j < 4; ++j) {
      s[j] = f2bf_trunc(ar[li * 2][j]);
      s[j + 4] = f2bf_trunc(ar[li * 2 + 1][j]);
    }
    *(short8*)(buf + L) = s;
  }
}
__device__ __forceinline__ void q_stageB(const short* __restrict__ gBt,
                                         char* buf, int tid) {
#pragma unroll
  for (int li = 0; li < 2; ++li) {
    int L = li * 4096 + tid * 16;
    int row = L >> 6;
    int cb = (L & 63) ^ (((row >> 1) & 3) << 4);
    gload16(gBt + (size_t)row * 1536 + (cb >> 1), buf + 8192 + L);
  }
}

__device__ void q_proj_body(int bid, const float* __restrict__ hs,
                            const short* __restrict__ wqT,
                            const float* __restrict__ rc,
                            const float* __restrict__ rsn,
                            short* __restrict__ qbuf, char* sm) {
  f32x4 acc[4][4] = {};
  int row0, col0;
  grid128(bid, row0, col0);

  const int tid = threadIdx.x;
  const int lane = tid & 63, wid = tid >> 6;
  const int wr = (wid >> 1) * 64, wc = (wid & 1) * 64;
  const int lr = lane & 15;
  const int hk = (lane >> 4) * 16;
  const int xr = ((lr >> 1) & 3) << 4;
  constexpr int NT = 48;

  const float* gAf = hs + (size_t)row0 * 1536;
  const short* gB = wqT + (size_t)col0 * 1536;
  char* p0 = sm;
  char* p1 = sm + 16384;
  char* p2 = sm + 32768;
  f32x4 arA[4], arB[4];

  q_issueA(gAf, tid, arA);
  q_stageB(gB, p0, tid);
  q_issueA(gAf + 32, tid, arB);
  q_stageB(gB + 32, p1, tid);
  asm volatile("s_waitcnt vmcnt(8)" ::: "memory");  // A0 landed
  q_writeA(p0, tid, arA);
  asm volatile("s_waitcnt vmcnt(6) lgkmcnt(0)" ::: "memory");  // B0 + write vis
  __builtin_amdgcn_s_barrier();

  for (int t = 0; t < NT; ++t) {
    if (t + 2 < NT) {
      if ((t & 1) == 0) q_issueA(gAf + (t + 2) * 32, tid, arA);
      else              q_issueA(gAf + (t + 2) * 32, tid, arB);
      q_stageB(gB + (t + 2) * 32, p2, tid);
    }
    __builtin_amdgcn_sched_barrier(0);
    compute32(p0, wr, wc, lr, hk, xr, acc);
    __builtin_amdgcn_sched_barrier(0);
    if (t + 2 < NT)
      asm volatile("s_waitcnt vmcnt(6)" ::: "memory");  // A(t+1),B(t+1) landed
    else
      asm volatile("s_waitcnt vmcnt(0)" ::: "memory");
    if (t + 1 < NT) {
      if ((t & 1) == 0) q_writeA(p1, tid, arB);
      else              q_writeA(p1, tid, arA);
    }
    asm volatile("s_waitcnt lgkmcnt(0)" ::: "memory");
    __builtin_amdgcn_s_barrier();
    char* tmp = p0; p0 = p1; p1 = p2; p2 = tmp;
  }

  const int lrow4 = (lane >> 4) * 4;
  const int h = (col0 + wc) >> 6;
#pragma unroll
  for (int m = 0; m < 4; ++m) {
#pragma unroll
    for (int r = 0; r < 4; ++r) {
      int grow = row0 + wr + m * 16 + lrow4 + r;
      int b = grow >> 11, t = grow & 2047;
      float v0 = acc[m][0][r], v1 = acc[m][1][r];
      float c0 = rc[t * 32 + lr], s0 = rsn[t * 32 + lr];
      float c1 = rc[t * 32 + 16 + lr], s1 = rsn[t * 32 + 16 + lr];
      float n0 = (v0 * c0 - v1 * s0) * QK_SCALE_LOG2E;
      float n1 = (v1 * c1 + v0 * s1) * QK_SCALE_LOG2E;
      short* ob = qbuf + ((size_t)(b * 24 + h) * 2048 + t) * 64;
      ob[lr] = f2bf(n0);
      ob[16 + lr] = f2bf(n1);
      ob[32 + lr] = f2bf(acc[m][2][r] * QK_SCALE_LOG2E);
      ob[48 + lr] = f2bf(acc[m][3][r] * QK_SCALE_LOG2E);
    }
  }
}

// ---------------------------------------------------------------------------
// KV body (text cols<768 -> K layout; cols>=768 -> permuted V^T layout).
// ---------------------------------------------------------------------------
__device__ void kv_body(int bx, int by, const short* __restrict__ textbf,
                        const short* __restrict__ ipbf,
                        const short* __restrict__ wkvT,
                        const short* __restrict__ wkvipT,
                        short* __restrict__ kbuf, short* __restrict__ vtbuf,
                        short* __restrict__ kipbuf,
                        short* __restrict__ vtipbuf, char* sm) {
  f32x4 acc[4][4] = {};
  const bool ip = by >= 16;
  const short* Abf = ip ? ipbf : textbf;
  const short* W = ip ? wkvipT : wkvT;
  short* kout = ip ? kipbuf : kbuf;
  short* vtout = ip ? vtipbuf : vtbuf;
  const int rlog2 = ip ? 6 : 9;
  const int row0 = (ip ? (by - 16) : by) * 128;
  const int col0 = bx * 128;
  gemm128p<768>(Abf, W, 768, 768, row0, col0, sm, acc);

  const int tid = threadIdx.x;
  const int lane = tid & 63, wid = tid >> 6;
  const int wr = (wid >> 1) * 64, wc = (wid & 1) * 64;
  const int lr = lane & 15, lrow4 = (lane >> 4) * 4;
  const int rmask = (1 << rlog2) - 1;
#pragma unroll
  for (int m = 0; m < 4; ++m) {
#pragma unroll
    for (int n = 0; n < 4; ++n) {
#pragma unroll
      for (int r = 0; r < 4; ++r) {
        int grow = row0 + wr + m * 16 + lrow4 + r;
        int gcol = col0 + wc + n * 16 + lr;
        int b = grow >> rlog2, key = grow & rmask;
        short val = f2bf(acc[m][n][r]);
        if (gcol < 768) {
          int kvh = gcol >> 6, d = gcol & 63;
          kout[((((size_t)(b * 12 + kvh)) << rlog2) + key) * 64 + d] = val;
        } else {
          int c2 = gcol - 768;
          int kvh = c2 >> 6, d = c2 & 63;
          int kp = (key & ~31) | (((key >> 2) & 3) << 3) |
                   (((key >> 4) & 1) << 2) | (key & 3);
          vtout[(((size_t)((b * 12 + kvh) * 64 + d)) << rlog2) + kp] = val;
        }
      }
    }
  }
}

// Combined q_proj + kv launch: blocks 0..767 q, 768..983 kv (12 x 18).
__global__ __launch_bounds__(256, 3) void qkv_kernel(
    const float* __restrict__ hs, const short* __restrict__ wqT,
    const float* __restrict__ rc, const float* __restrict__ rsn,
    short* __restrict__ qbuf, const short* __restrict__ textbf,
    const short* __restrict__ ipbf, const short* __restrict__ wkvT,
    const short* __restrict__ wkvipT, short* __restrict__ kbuf,
    short* __restrict__ vtbuf, short* __restrict__ kipbuf,
    short* __restrict__ vtipbuf) {
  __shared__ char sm[49152];
  if (blockIdx.x < 768) {
    q_proj_body(blockIdx.x, hs, wqT, rc, rsn, qbuf, sm);
  } else {
    int bid = blockIdx.x - 768;
    kv_body(bid % 12, bid / 12, textbf, ipbf, wkvT, wkvipT, kbuf, vtbuf,
            kipbuf, vtipbuf, sm);
  }
}

// ---------------------------------------------------------------------------
// Output projection: 3-buffer LDS core + plain bias/resid epilogue.
// ---------------------------------------------------------------------------
__global__ __launch_bounds__(256, 3) void o_proj_128p(
    const short* __restrict__ attnbf, const short* __restrict__ woT,
    const float* __restrict__ bo, const float* __restrict__ resid,
    float* __restrict__ out) {
  __shared__ char sm[49152];
  f32x4 acc[4][4] = {};
  int row0, col0;
  grid128(blockIdx.x, row0, col0);
  gemm128p<1536>(attnbf, woT, 1536, 1536, row0, col0, sm, acc);

  const int lane = threadIdx.x & 63, wid = threadIdx.x >> 6;
  const int wr = (wid >> 1) * 64, wc = (wid & 1) * 64;
  const int lr = lane & 15, lrow4 = (lane >> 4) * 4;
#pragma unroll
  for (int m = 0; m < 4; ++m) {
#pragma unroll
    for (int n = 0; n < 4; ++n) {
#pragma unroll
      for (int r = 0; r < 4; ++r) {
        int grow = row0 + wr + m * 16 + lrow4 + r;
        int gcol = col0 + wc + n * 16 + lr;
        size_t off = (size_t)grow * 1536 + gcol;
        out[off] = acc[m][n][r] + bo[gcol] + resid[off];
      }
    }
  }
}

// ---------------------------------------------------------------------------
// Attention: swapped QK^T, in-register P, per-lane deferred max, 3-buffer
// counted-vmcnt K/V pipeline (R16 proven).
// ---------------------------------------------------------------------------
__device__ __forceinline__ void stage_tile(const short* __restrict__ ks,
                                           const short* __restrict__ vs,
                                           int vstr, short* kb, short* vb,
                                           int tid) {
#pragma unroll
  for (int q = 0; q < 2; ++q) {
    int L = q * 4096 + tid * 16;
    int row = L >> 7;
    int sc = ((L & 127) ^ ((row & 7) << 4)) >> 1;
    gload16(ks + row * 64 + sc, (char*)kb + L);
    gload16(vs + (size_t)row * vstr + sc, (char*)vb + L);
  }
}

__device__ __forceinline__ void attn_tile(const short* kb, const short* vb,
                                          const short8 qf[2],
                                          float& m_run, float& l_run,
                                          f32x4 o_acc[4], int lane) {
  const int lr = lane & 15, hi = lane >> 4;
  f32x4 s[4];
#pragma unroll
  for (int nf = 0; nf < 4; ++nf) {
    int row = nf * 16 + lr;
    int rx = (row & 7) << 4;
    const char* base = (const char*)kb + row * 128;
    short8 k0 = *(const short8*)(base + ((hi * 16) ^ rx));
    short8 k1 = *(const short8*)(base + ((64 + hi * 16) ^ rx));
    f32x4 a = {0.f, 0.f, 0.f, 0.f};
    a = MFMA16(k0, qf[0], a);
    a = MFMA16(k1, qf[1], a);
    s[nf] = a;
  }
  float mx = fmaxf(fmaxf(s[0][0], s[0][1]), fmaxf(s[0][2], s[0][3]));
#pragma unroll
  for (int nf = 1; nf < 4; ++nf)
    mx = fmaxf(mx, fmaxf(fmaxf(s[nf][0], s[nf][1]), fmaxf(s[nf][2], s[nf][3])));
  if (__any(mx - m_run > 8.0f)) {
    float mr = fmaxf(mx, __shfl_xor(mx, 16));
    mr = fmaxf(mr, __shfl_xor(mr, 32));
    float mn = fmaxf(m_run, mr);
    float corr = __builtin_amdgcn_exp2f(m_run - mn);
    m_run = mn;
    l_run *= corr;
#pragma unroll
    for (int r = 0; r < 4; ++r) {
      float cr = __shfl(corr, hi * 4 + r);
#pragma unroll
      for (int no = 0; no < 4; ++no) o_acc[no][r] *= cr;
    }
  }
  short8 pa[2];
#pragma unroll
  for (int nf = 0; nf < 4; ++nf) {
#pragma unroll
    for (int r = 0; r < 4; ++r) {
      float p = __builtin_amdgcn_exp2f(s[nf][r] - m_run);
      l_run += p;
      pa[nf >> 1][(nf & 1) * 4 + r] = f2bf_trunc(p);
    }
  }
#pragma unroll
  for (int ks = 0; ks < 2; ++ks) {
#pragma unroll
    for (int no = 0; no < 4; ++no) {
      int row = no * 16 + lr;
      int rx = (row & 7) << 4;
      short8 vf = *(const short8*)((const char*)vb + row * 128 +
                                   ((ks * 64 + hi * 16) ^ rx));
      o_acc[no] = MFMA16(pa[ks], vf, o_acc[no]);
    }
  }
}

__global__ __launch_bounds__(256, 3) void attn_kernel(
    const short* __restrict__ qbuf, const short* __restrict__ kbuf,
    const short* __restrict__ vtbuf, const short* __restrict__ kipbuf,
    const short* __restrict__ vtipbuf, short* __restrict__ attn_out) {
  const int tid = threadIdx.x;
  const int lane = tid & 63, wid = tid >> 6;
  const int f = (blockIdx.x & 7) * 384 + (blockIdx.x >> 3);
  const int qt = f & 31;
  const int h = (f >> 5) % 24;
  const int b = f / (32 * 24);
  const int kvh = h >> 1;
  const int lr = lane & 15, hi = lane >> 4;

  __shared__ short skv_k[3 * 64 * 64];
  __shared__ short skv_v[3 * 64 * 64];

  const short* qp = qbuf + (size_t)(b * 24 + h) * 2048 * 64;
  const short* kp = kbuf + (size_t)(b * 12 + kvh) * 512 * 64;
  const short* vp = vtbuf + (size_t)(b * 12 + kvh) * 64 * 512;
  const short* kip = kipbuf + (size_t)(b * 12 + kvh) * 64 * 64;
  const short* vip = vtipbuf + (size_t)(b * 12 + kvh) * 64 * 64;

  const int q0 = qt * 64 + wid * 16;
  short8 qf[2];
  qf[0] = *(const short8*)(qp + (size_t)(q0 + lr) * 64 + hi * 8);
  qf[1] = *(const short8*)(qp + (size_t)(q0 + lr) * 64 + 32 + hi * 8);

  float m1 = -1.0e30f, l1 = 0.f, m2 = -1.0e30f, l2 = 0.f;
  f32x4 oacc1[4] = {}, oacc2[4] = {};

  stage_tile(kp, vp, 512, skv_k, skv_v, tid);
  stage_tile(kp + 64 * 64, vp + 64, 512, skv_k + 4096, skv_v + 4096, tid);
  asm volatile("s_waitcnt vmcnt(4)" ::: "memory");
  __builtin_amdgcn_s_barrier();

  for (int t = 0; t < 9; ++t) {
    if (t + 2 <= 8) {
      int tt = t + 2;
      const short* ks_ = (tt < 8) ? kp + tt * 64 * 64 : kip;
      const short* vs_ = (tt < 8) ? vp + tt * 64 : vip;
      int vstr = (tt < 8) ? 512 : 64;
      int bsel = tt % 3;
      stage_tile(ks_, vs_, vstr, skv_k + bsel * 4096, skv_v + bsel * 4096, tid);
    }
    __builtin_amdgcn_sched_barrier(0);
    int cur = t % 3;
    if (t < 8)
      attn_tile(skv_k + cur * 4096, skv_v + cur * 4096, qf, m1, l1, oacc1, lane);
    else
      attn_tile(skv_k + cur * 4096, skv_v + cur * 4096, qf, m2, l2, oacc2, lane);
    __builtin_amdgcn_sched_barrier(0);
    if (t + 2 <= 8)
      asm volatile("s_waitcnt vmcnt(4)" ::: "memory");
    else if (t + 1 <= 8)
      asm volatile("s_waitcnt vmcnt(0)" ::: "memory");
    __builtin_amdgcn_s_barrier();
  }

  l1 += __shfl_xor(l1, 16); l1 += __shfl_xor(l1, 32);
  l2 += __shfl_xor(l2, 16); l2 += __shfl_xor(l2, 32);
  float inv1 = 1.0f / l1, inv2 = 1.0f / l2;
#pragma unroll
  for (int r = 0; r < 4; ++r) {
    float i1 = __shfl(inv1, hi * 4 + r);
    float i2 = __shfl(inv2, hi * 4 + r);
    int grow = b * 2048 + q0 + hi * 4 + r;
#pragma unroll
    for (int no = 0; no < 4; ++no) {
      float val = oacc1[no][r] * i1 + oacc2[no][r] * i2;
      attn_out[(size_t)grow * 1536 + h * 64 + no * 16 + lr] = f2bf(val);
    }
  }
}

// ---------------------------------------------------------------------------
extern "C" void kernel_launch(void* const* d_in, const int* in_sizes, int n_in,
                              void* d_out, int out_size, void* d_ws, size_t ws_size,
                              hipStream_t stream) {
  const float* hs = (const float*)d_in[0];
  const float* enc = (const float*)d_in[1];
  const float* rc = (const float*)d_in[2];
  const float* rsn = (const float*)d_in[3];
  const float* wq = (const float*)d_in[4];
  const float* wk = (const float*)d_in[5];
  const float* wv = (const float*)d_in[6];
  const float* wkip = (const float*)d_in[7];
  const float* wvip = (const float*)d_in[8];
  const float* wo = (const float*)d_in[9];
  const float* bo = (const float*)d_in[10];
  float* out = (float*)d_out;

  char* ws = (char*)d_ws;
  short* attnbuf = (short*)(ws + 0);          // 25165824
  short* qbuf    = (short*)(ws + 25165824);   // 25165824
  short* kbuf    = (short*)(ws + 50331648);   //  3145728
  short* vtbuf   = (short*)(ws + 53477376);   //  3145728
  short* kipbuf  = (short*)(ws + 56623104);   //   393216
  short* vtipbuf = (short*)(ws + 57016320);   //   393216
  short* textbf  = (short*)(ws + 57409536);   //  3145728
  short* ipbf    = (short*)(ws + 60555264);   //   393216
  short* wqT     = (short*)(ws + 60948480);   //  4718592
  short* woT     = (short*)(ws + 65667072);   //  4718592
  short* wkvT    = (short*)(ws + 70385664);   //  2359296
  short* wkvipT  = (short*)(ws + 72744960);   //  2359296
  // total 75104256 bytes

  // --- fused pre-pass: enc pack + all weight transposes ---
  prepass_kernel<<<8640, 256, 0, stream>>>(enc, textbf, ipbf, wq, wo, wk, wv,
                                           wkip, wvip, wqT, woT, wkvT, wkvipT);

  // --- fused Q projection + K/V projections ---
  qkv_kernel<<<984, 256, 0, stream>>>(hs, wqT, rc, rsn, qbuf, textbf, ipbf,
                                      wkvT, wkvipT, kbuf, vtbuf, kipbuf,
                                      vtipbuf);

  // --- attention ---
  attn_kernel<<<3072, 256, 0, stream>>>(qbuf, kbuf, vtbuf, kipbuf,
                                        vtipbuf, attnbuf);

  // --- output projection + bias + residual ---
  o_proj_128p<<<768, 256, 0, stream>>>(attnbuf, woT, bo, hs, out);
}